// Round 1
// baseline (615.539 us; speedup 1.0000x reference)
//
#include <hip/hip_runtime.h>
#include <math.h>

#define B    1024
#define NI   32
#define NH   1024
#define RPB  8           // batch rows per block
#define NTHR 512         // 8 waves

// ws layout (floats), all degree-sorted ("s" = sorted hidden index):
//  W1s [NH][NI]  masked W1 rows             @ 0
//  b1s [NH]                                  @ 32768
//  b2s [NH]                                  @ 33792
//  W2t [NH][NH]  W2t[sh][sg] = M2[g][h]      @ 34816   (transposed + masked)
//  W3s [64][NH]  masked, sorted columns      @ 1083392
#define OFF_W1S 0
#define OFF_B1S 32768
#define OFF_B2S 33792
#define OFF_W2T 34816
#define OFF_W3S 1083392
// total = 1148928 floats = ~4.6 MB of ws

// sorted index -> (degree, original h).  deg counts: deg0 has 34 units, deg1..30 have 33.
__device__ __forceinline__ void sorted_to_orig(int s, int& d, int& orig) {
    int k;
    if (s < 34) { d = 0; k = s; }
    else        { d = (s - 34) / 33 + 1; k = (s - 34) % 33; }
    orig = d + 31 * k;
}

// Permute + mask b1,b2,W1,W3 into sorted order.  grid: 4x256
__global__ void prep_small(const float* __restrict__ W1,
                           const float* __restrict__ b1,
                           const float* __restrict__ b2,
                           const float* __restrict__ W3,
                           float* __restrict__ ws) {
    int s = blockIdx.x * blockDim.x + threadIdx.x;
    if (s >= NH) return;
    int d, orig;
    sorted_to_orig(s, d, orig);
    ws[OFF_B1S + s] = b1[orig];
    ws[OFF_B2S + s] = b2[orig];
#pragma unroll
    for (int j = 0; j < NI; ++j)
        ws[OFF_W1S + s * NI + j] = (d >= j) ? W1[orig * NI + j] : 0.0f;
    for (int o = 0; o < 2 * NI; ++o) {
        int od = (o & 31) - 1;                      // out_deg_output
        ws[OFF_W3S + o * NH + s] = (od >= d) ? W3[o * NH + orig] : 0.0f;
    }
}

// W2t[sh][sg] = m2-masked W2[orig_g][orig_h], coalesced writes, gathered reads.
// grid: NH blocks (one per sorted-h row) x 256
__global__ void prep_w2(const float* __restrict__ W2, float* __restrict__ ws) {
    int sh = blockIdx.x;
    int dh, oh;
    sorted_to_orig(sh, dh, oh);
    float* dst = ws + OFF_W2T + (size_t)sh * NH;
    for (int sg = threadIdx.x; sg < NH; sg += blockDim.x) {
        int dg, og;
        sorted_to_orig(sg, dg, og);
        dst[sg] = (dg >= dh) ? W2[og * NH + oh] : 0.0f;
    }
}

// One block = 8 batch rows; full 32-step scan in-block, state in LDS.
__global__ __launch_bounds__(NTHR) void made_scan(
        const float* __restrict__ inputs,
        const float* __restrict__ b3,
        const float* __restrict__ ws,
        float* __restrict__ out) {
    __shared__ float z2s[RPB][NH];        // 32 KB running layer-2 preacts
    __shared__ float a1s[RPB][40];        // relu(z1) of newly-final h1 units
    __shared__ float xs [RPB][NI + 1];    // generated x (pad: kill bank conflicts)
    __shared__ float xin[RPB][NI];        // cached inputs

    const int tid = threadIdx.x;
    const int rg0 = blockIdx.x * RPB;

    const float* W1s = ws + OFF_W1S;
    const float* b1s = ws + OFF_B1S;
    const float* b2s = ws + OFF_B2S;
    const float* W2t = ws + OFF_W2T;
    const float* W3s = ws + OFF_W3S;

    for (int p = tid; p < RPB * NI; p += NTHR) {
        int r = p >> 5, j = p & 31;
        xin[r][j] = inputs[(rg0 + r) * NI + j];
    }
    for (int g = tid; g < NH; g += NTHR) {
        float bb = b2s[g];
#pragma unroll
        for (int r = 0; r < RPB; ++r) z2s[r][g] = bb;
    }
    float Jacc = 0.0f;                    // live in lane 0 of each wave
    __syncthreads();

    for (int i = 0; i < NI; ++i) {
        const int dd   = i - 1;                              // degree finalized this step
        const int goff = (i <= 1) ? 0 : (33 * dd + 1);       // off(dd): first sorted idx of deg dd
        const int cnt  = (i == 0) ? 0 : ((dd == 0) ? 34 : 33);

        // ---- Phase A: fresh z1 for h1 units with deg == i-1 (use x_0..x_{i-1})
        if (i > 0) {
            for (int p = tid; p < cnt * RPB; p += NTHR) {
                int r = p & 7, u = p >> 3;
                int s = goff + u;
                float z = b1s[s];
                const float* wrow = W1s + s * NI;
                for (int j = 0; j < i; ++j) z = fmaf(xs[r][j], wrow[j], z);
                a1s[r][u] = fmaxf(z, 0.0f);
            }
        }
        __syncthreads();

        // ---- Phase B: z2 suffix [goff,NH) += A1[R x cnt] * W2t[cnt x suffix]
        if (i > 0) {
            int gl[2];
#pragma unroll
            for (int m = 0; m < 2; ++m) gl[m] = goff + tid + m * NTHR;
            float acc[2][RPB];
#pragma unroll
            for (int m = 0; m < 2; ++m)
                if (gl[m] < NH) {
#pragma unroll
                    for (int r = 0; r < RPB; ++r) acc[m][r] = z2s[r][gl[m]];
                }
            for (int u = 0; u < cnt; ++u) {
                float av[RPB];
#pragma unroll
                for (int r = 0; r < RPB; ++r) av[r] = a1s[r][u];   // LDS broadcast
                const float* wrow = W2t + (size_t)(goff + u) * NH;
#pragma unroll
                for (int m = 0; m < 2; ++m)
                    if (gl[m] < NH) {
                        float w = wrow[gl[m]];                     // coalesced, reused x8
#pragma unroll
                        for (int r = 0; r < RPB; ++r)
                            acc[m][r] = fmaf(av[r], w, acc[m][r]);
                    }
            }
#pragma unroll
            for (int m = 0; m < 2; ++m)
                if (gl[m] < NH) {
#pragma unroll
                    for (int r = 0; r < RPB; ++r) z2s[r][gl[m]] = acc[m][r];
                }
        }
        __syncthreads();

        // ---- Phase C: outputs i and 32+i from z2 prefix [0, off(i)); one wave per row
        {
            const int L    = goff + cnt;      // off(i)
            const int r    = tid >> 6;
            const int lane = tid & 63;
            const float* w3a = W3s + i * NH;
            const float* w3b = W3s + (NI + i) * NH;
            float s0 = 0.0f, s1 = 0.0f;
            for (int g = lane; g < L; g += 64) {
                float h = fmaxf(z2s[r][g], 0.0f);
                s0 = fmaf(w3a[g], h, s0);
                s1 = fmaf(w3b[g], h, s1);
            }
#pragma unroll
            for (int o = 32; o > 0; o >>= 1) {
                s0 += __shfl_down(s0, o, 64);
                s1 += __shfl_down(s1, o, 64);
            }
            if (lane == 0) {
                float p0 = s0 + b3[i];
                float p1 = s1 + b3[NI + i];
                float a  = tanhf(p1);
                xs[r][i] = xin[r][i] * expf(a) + p0;
                Jacc    -= a;
            }
        }
        __syncthreads();
    }

    for (int p = tid; p < RPB * NI; p += NTHR) {
        int r = p >> 5, j = p & 31;
        out[(rg0 + r) * NI + j] = xs[r][j];
    }
    if ((tid & 63) == 0) out[B * NI + rg0 + (tid >> 6)] = Jacc;
}

extern "C" void kernel_launch(void* const* d_in, const int* in_sizes, int n_in,
                              void* d_out, int out_size, void* d_ws, size_t ws_size,
                              hipStream_t stream) {
    const float* inputs = (const float*)d_in[0];
    const float* W1     = (const float*)d_in[1];
    const float* b1     = (const float*)d_in[2];
    const float* W2     = (const float*)d_in[3];
    const float* b2     = (const float*)d_in[4];
    const float* W3     = (const float*)d_in[5];
    const float* b3     = (const float*)d_in[6];
    float* out = (float*)d_out;
    float* ws  = (float*)d_ws;

    prep_small<<<4, 256, 0, stream>>>(W1, b1, b2, W3, ws);
    prep_w2<<<NH, 256, 0, stream>>>(W2, ws);
    made_scan<<<B / RPB, NTHR, 0, stream>>>(inputs, b3, ws, out);
}

// Round 2
// 547.641 us; speedup vs baseline: 1.1240x; 1.1240x over previous
//
#include <hip/hip_runtime.h>
#include <math.h>

#define B    1024
#define NI   32
#define NH   1024

// ws layout (floats), degree-sorted hidden index "s":
//   W1t [NI][NH] : W1t[j][s] = m1-masked W1[orig(s)][j]
//   b1s [NH+64]  : sorted b1, +64 zero pad (lanes >= cnt overread harmlessly)
//   b2s [NH]
//   W2t [NH][NH] : W2t[sh][sg] = m2-masked W2[og][oh]
//   W3s [64][NH] : m3-masked, sorted columns
#define OFF_W1T 0
#define OFF_B1S (NI * NH)              // 32768
#define OFF_B2S (OFF_B1S + NH + 64)    // 33856  (16-float aligned)
#define OFF_W2T (OFF_B2S + NH)         // 34880
#define OFF_W3S (OFF_W2T + NH * NH)    // 1083456
// total floats = 1083456 + 64*1024 = 1148992  (~4.6 MB)

// sorted s -> (deg, orig h). deg0 has 34 units, deg1..30 have 33.
__device__ __forceinline__ void s2o(int s, int& d, int& orig) {
    int k;
    if (s < 34) { d = 0; k = s; }
    else        { d = (s - 34) / 33 + 1; k = (s - 34) % 33; }
    orig = d + 31 * k;
}

__global__ void prep_b(const float* __restrict__ b1, const float* __restrict__ b2,
                       float* __restrict__ ws) {
    int s = blockIdx.x * blockDim.x + threadIdx.x;
    if (s >= NH) return;
    int d, o; s2o(s, d, o);
    ws[OFF_B1S + s] = b1[o];
    ws[OFF_B2S + s] = b2[o];
    if (s < 64) ws[OFF_B1S + NH + s] = 0.0f;   // pad
}

__global__ void prep_w1t(const float* __restrict__ W1, float* __restrict__ ws) {
    int idx = blockIdx.x * blockDim.x + threadIdx.x;   // 32*1024 threads
    int s = idx & (NH - 1), j = idx >> 10;
    int d, o; s2o(s, d, o);
    ws[OFF_W1T + j * NH + s] = (d >= j) ? W1[o * NI + j] : 0.0f;
}

__global__ void prep_w3s(const float* __restrict__ W3, float* __restrict__ ws) {
    int idx = blockIdx.x * blockDim.x + threadIdx.x;   // 64*1024 threads
    int s = idx & (NH - 1), o = idx >> 10;
    int d, orig; s2o(s, d, orig);
    int od = (o & 31) - 1;
    ws[OFF_W3S + o * NH + s] = (od >= d) ? W3[o * NH + orig] : 0.0f;
}

__global__ void prep_w2t(const float* __restrict__ W2, float* __restrict__ ws) {
    int idx = blockIdx.x * blockDim.x + threadIdx.x;   // 1024*1024 threads
    int sg = idx & (NH - 1), sh = idx >> 10;
    int dg, og; s2o(sg, dg, og);
    int dh, oh; s2o(sh, dh, oh);
    ws[OFF_W2T + (size_t)sh * NH + sg] = (dg >= dh) ? W2[og * NH + oh] : 0.0f;
}

template <int QMIN>
__device__ __forceinline__ void phaseB(float4 (&z2)[4], const float* rowbase,
                                       float a1, int cnt, int lane) {
    for (int u = 0; u < cnt; ++u) {
        float av = __shfl(a1, u, 64);
        const float4* pu = (const float4*)(rowbase + (size_t)u * NH) + lane;
#pragma unroll
        for (int q = QMIN; q < 4; ++q) {
            float4 w = pu[q * 64];          // +q*256 floats, coalesced dwordx4
            z2[q].x = fmaf(av, w.x, z2[q].x);
            z2[q].y = fmaf(av, w.y, z2[q].y);
            z2[q].z = fmaf(av, w.z, z2[q].z);
            z2[q].w = fmaf(av, w.w, z2[q].w);
        }
    }
}

// one wave = one batch row; z2 state in 16 VGPRs/lane; no LDS, no phase barriers
__global__ __launch_bounds__(256) void made_scan(
        const float* __restrict__ inputs,
        const float* __restrict__ b3,
        const float* __restrict__ ws,
        float* __restrict__ out) {
    const int lane = threadIdx.x & 63;
    const int row  = blockIdx.x * 4 + (threadIdx.x >> 6);

    const float* W1t = ws + OFF_W1T;
    const float* b1s = ws + OFF_B1S;
    const float* b2s = ws + OFF_B2S;
    const float* W2t = ws + OFF_W2T;
    const float* W3s = ws + OFF_W3S;

    float4 z2[4];                           // g = q*256 + lane*4 + c
#pragma unroll
    for (int q = 0; q < 4; ++q) z2[q] = *((const float4*)(b2s + q * 256) + lane);

    float xin  = (lane < NI) ? inputs[row * NI + lane] : 0.0f;
    float xreg = 0.0f;                      // x_j lives in lane j
    float Jacc = 0.0f;

    for (int i = 0; i < NI; ++i) {
        __syncthreads();                    // keep 4 waves together -> L1 weight reuse
        const int dd   = i - 1;
        const int goff = (i <= 1) ? 0 : (33 * dd + 1);
        const int cnt  = (i == 0) ? 0 : ((dd == 0) ? 34 : 33);

        // ---- Phase A: fresh z1 for units finalized this step (lane u = unit goff+u)
        float a1 = 0.0f;
        if (i > 0) {
            float z = b1s[goff + lane];
            for (int j = 0; j < i; ++j) {
                float xj = __shfl(xreg, j, 64);
                z = fmaf(xj, W1t[j * NH + goff + lane], z);
            }
            a1 = fmaxf(z, 0.0f);
        }

        // ---- Phase B: z2[g >= goff] += a1[u] * W2t[goff+u][g] (masked below goff)
        if (i > 0) {
            const float* rowbase = W2t + (size_t)goff * NH;
            switch ((i - 1) >> 3) {         // qmin: chunks entirely below goff skipped
                case 0: phaseB<0>(z2, rowbase, a1, cnt, lane); break;
                case 1: phaseB<1>(z2, rowbase, a1, cnt, lane); break;
                case 2: phaseB<2>(z2, rowbase, a1, cnt, lane); break;
                default: phaseB<3>(z2, rowbase, a1, cnt, lane); break;
            }
        }

        // ---- Phase C: p[i], p[32+i] from masked W3s rows (zeros beyond prefix)
        {
            const int L  = (i == 0) ? 0 : (33 * i + 1);
            const int qc = (L + 255) >> 8;
            const float* w3a = W3s + (size_t)i * NH;
            const float* w3b = W3s + (size_t)(NI + i) * NH;
            float s0 = 0.0f, s1 = 0.0f;
#pragma unroll
            for (int q = 0; q < 4; ++q) {
                if (q >= qc) continue;      // uniform branch
                float4 wa = *((const float4*)(w3a + q * 256) + lane);
                float4 wb = *((const float4*)(w3b + q * 256) + lane);
                float hx = fmaxf(z2[q].x, 0.0f), hy = fmaxf(z2[q].y, 0.0f);
                float hz = fmaxf(z2[q].z, 0.0f), hw = fmaxf(z2[q].w, 0.0f);
                s0 = fmaf(wa.x, hx, s0); s1 = fmaf(wb.x, hx, s1);
                s0 = fmaf(wa.y, hy, s0); s1 = fmaf(wb.y, hy, s1);
                s0 = fmaf(wa.z, hz, s0); s1 = fmaf(wb.z, hz, s1);
                s0 = fmaf(wa.w, hw, s0); s1 = fmaf(wb.w, hw, s1);
            }
#pragma unroll
            for (int m = 32; m >= 1; m >>= 1) {
                s0 += __shfl_xor(s0, m, 64);
                s1 += __shfl_xor(s1, m, 64);
            }
            float p0 = s0 + b3[i];
            float p1 = s1 + b3[NI + i];
            float a  = tanhf(p1);
            float xi = fmaf(__shfl(xin, i, 64), expf(a), p0);
            if (lane == i) xreg = xi;
            Jacc -= a;
        }
    }

    if (lane < NI) out[row * NI + lane] = xreg;
    if (lane == 0) out[B * NI + row] = Jacc;
}

extern "C" void kernel_launch(void* const* d_in, const int* in_sizes, int n_in,
                              void* d_out, int out_size, void* d_ws, size_t ws_size,
                              hipStream_t stream) {
    const float* inputs = (const float*)d_in[0];
    const float* W1     = (const float*)d_in[1];
    const float* b1     = (const float*)d_in[2];
    const float* W2     = (const float*)d_in[3];
    const float* b2     = (const float*)d_in[4];
    const float* W3     = (const float*)d_in[5];
    const float* b3     = (const float*)d_in[6];
    float* out = (float*)d_out;
    float* ws  = (float*)d_ws;

    prep_b  <<<4,    256, 0, stream>>>(b1, b2, ws);
    prep_w1t<<<128,  256, 0, stream>>>(W1, ws);
    prep_w3s<<<256,  256, 0, stream>>>(W3, ws);
    prep_w2t<<<4096, 256, 0, stream>>>(W2, ws);
    made_scan<<<B / 4, 256, 0, stream>>>(inputs, b3, ws, out);
}

// Round 3
// 205.307 us; speedup vs baseline: 2.9981x; 2.6674x over previous
//
#include <hip/hip_runtime.h>
#include <math.h>

#define B    1024
#define NI   32
#define NH   1024
#define WPB  4      // slice-waves per row (each owns 256 of the 1024 z2 entries)

// ws layout (floats), degree-sorted hidden index "s":
//   W1t [NI][NH] : W1t[j][s] = m1-masked W1[orig(s)][j]
//   b1s [NH+64]  : sorted b1, zero pad (lanes overread harmlessly)
//   b2s [NH]
//   W2t [NH][NH] : W2t[sh][sg] = m2-masked W2[og][oh]
//   W3s [64][NH] : m3-masked, sorted columns
#define OFF_W1T 0
#define OFF_B1S (NI * NH)              // 32768
#define OFF_B2S (OFF_B1S + NH + 64)    // 33856
#define OFF_W2T (OFF_B2S + NH)         // 34880
#define OFF_W3S (OFF_W2T + NH * NH)    // 1083456
// total = 1148992 floats (~4.6 MB). Phase-B zero-weighted overreads of up to
// ~3K floats past W2T land inside W3S (finite, multiplied by 0.0) — in-bounds.

// sorted s -> (deg, orig h). deg0 has 34 units, deg1..30 have 33.
__device__ __forceinline__ void s2o(int s, int& d, int& orig) {
    int k;
    if (s < 34) { d = 0; k = s; }
    else        { d = (s - 34) / 33 + 1; k = (s - 34) % 33; }
    orig = d + 31 * k;
}

// One kernel, blockIdx ranges: [0,4096) W2t, [4096,4224) W1t, [4224,4480) W3s, [4480,4484) biases
__global__ void prep_all(const float* __restrict__ W1, const float* __restrict__ b1,
                         const float* __restrict__ W2, const float* __restrict__ b2,
                         const float* __restrict__ W3, float* __restrict__ ws) {
    const int bid = blockIdx.x, t = threadIdx.x;
    if (bid < 4096) {                                   // W2t: 1M elements
        int idx = bid * 256 + t;
        int sg = idx & (NH - 1), sh = idx >> 10;
        int dg, og; s2o(sg, dg, og);
        int dh, oh; s2o(sh, dh, oh);
        ws[OFF_W2T + (size_t)sh * NH + sg] = (dg >= dh) ? W2[og * NH + oh] : 0.0f;
    } else if (bid < 4224) {                            // W1t: 32K elements
        int idx = (bid - 4096) * 256 + t;
        int s = idx & (NH - 1), j = idx >> 10;
        int d, o; s2o(s, d, o);
        ws[OFF_W1T + j * NH + s] = (d >= j) ? W1[o * NI + j] : 0.0f;
    } else if (bid < 4480) {                            // W3s: 64K elements
        int idx = (bid - 4224) * 256 + t;
        int s = idx & (NH - 1), o = idx >> 10;
        int d, orig; s2o(s, d, orig);
        int od = (o & 31) - 1;
        ws[OFF_W3S + o * NH + s] = (od >= d) ? W3[o * NH + orig] : 0.0f;
    } else {                                            // biases
        int s = (bid - 4480) * 256 + t;
        int d, o; s2o(s, d, o);
        ws[OFF_B1S + s] = b1[o];
        ws[OFF_B2S + s] = b2[o];
        if (s < 64) ws[OFF_B1S + NH + s] = 0.0f;        // pad
    }
}

// One block = one batch row; 4 waves each own a 256-wide z2 slice (1 float4/lane).
// Cross-wave communication: only the phase-C partial sums (1 barrier/step).
__global__ __launch_bounds__(256, 4) void made_scan(
        const float* __restrict__ inputs,
        const float* __restrict__ b3,
        const float* __restrict__ ws,
        float* __restrict__ out) {
    __shared__ float part[2][WPB][2];      // double-buffered C partials
    __shared__ float a1buf[WPB][40];       // per-wave a1 copy (pad->36 zeros)
    __shared__ float xsbuf[WPB][NI];       // per-wave generated-x copy

    const int tid   = threadIdx.x;
    const int lane  = tid & 63;
    const int w     = tid >> 6;
    const int row   = blockIdx.x;
    const int gbase = w * 256;

    const float* W1t = ws + OFF_W1T;
    const float* b1s = ws + OFF_B1S;
    const float* b2s = ws + OFF_B2S;
    const float* W2t = ws + OFF_W2T;
    const float* W3s = ws + OFF_W3S;

    float4 z2 = ((const float4*)(b2s + gbase))[lane];   // g = gbase + lane*4 + c
    float xin  = (lane < NI) ? inputs[row * NI + lane] : 0.0f;
    float b3v  = b3[lane];
    float Jacc = 0.0f;
    if (lane < NI) xsbuf[w][lane] = 0.0f;               // x starts at zero (exact ref)

    for (int i = 0; i < NI; ++i) {
        const int goff = (i <= 1) ? 0 : (33 * (i - 1) + 1);
        const int cnt  = (i == 0) ? 0 : ((i == 1) ? 34 : 33);
        const bool doB = (i > 0) && (gbase + 256 > goff);

        if (doB) {
            // ---- Phase A: a1 for units finalized this step (lane u = goff+u)
            float z = b1s[goff + lane];
            for (int j4 = 0; j4 < i; j4 += 4) {
                float4 xv = *(const float4*)&xsbuf[w][j4];   // broadcast; zeros for j>=i
                z = fmaf(xv.x, W1t[(j4 + 0) * NH + goff + lane], z);
                z = fmaf(xv.y, W1t[(j4 + 1) * NH + goff + lane], z);
                z = fmaf(xv.z, W1t[(j4 + 2) * NH + goff + lane], z);
                z = fmaf(xv.w, W1t[(j4 + 3) * NH + goff + lane], z);
            }
            if (lane < 40) a1buf[w][lane] = (lane < cnt) ? fmaxf(z, 0.0f) : 0.0f;

            // ---- Phase B: z2 slice += sum_u a1[u] * W2t[goff+u][slice]
            const float* rb = W2t + (size_t)goff * NH + gbase;
#pragma unroll
            for (int u4 = 0; u4 < 36; u4 += 4) {
                float4 av = *(const float4*)&a1buf[w][u4];   // LDS broadcast b128
                const float4* pr = (const float4*)(rb + (size_t)u4 * NH) + lane;
                float4 w0 = pr[0];
                float4 w1 = pr[256];
                float4 w2 = pr[512];
                float4 w3r = pr[768];
                z2.x = fmaf(av.x, w0.x, z2.x); z2.y = fmaf(av.x, w0.y, z2.y);
                z2.z = fmaf(av.x, w0.z, z2.z); z2.w = fmaf(av.x, w0.w, z2.w);
                z2.x = fmaf(av.y, w1.x, z2.x); z2.y = fmaf(av.y, w1.y, z2.y);
                z2.z = fmaf(av.y, w1.z, z2.z); z2.w = fmaf(av.y, w1.w, z2.w);
                z2.x = fmaf(av.z, w2.x, z2.x); z2.y = fmaf(av.z, w2.y, z2.y);
                z2.z = fmaf(av.z, w2.z, z2.z); z2.w = fmaf(av.z, w2.w, z2.w);
                z2.x = fmaf(av.w, w3r.x, z2.x); z2.y = fmaf(av.w, w3r.y, z2.y);
                z2.z = fmaf(av.w, w3r.z, z2.z); z2.w = fmaf(av.w, w3r.w, z2.w);
            }
        }

        // ---- Phase C: slice-partial of p[i], p[32+i] (W3s zeros beyond prefix)
        const int L = (i == 0) ? 0 : (33 * i + 1);
        float s0 = 0.0f, s1 = 0.0f;
        if (gbase < L) {
            float4 wa = ((const float4*)(W3s + (size_t)i * NH + gbase))[lane];
            float4 wb = ((const float4*)(W3s + (size_t)(NI + i) * NH + gbase))[lane];
            float hx = fmaxf(z2.x, 0.0f), hy = fmaxf(z2.y, 0.0f);
            float hz = fmaxf(z2.z, 0.0f), hw = fmaxf(z2.w, 0.0f);
            s0 = fmaf(wa.x, hx, s0); s1 = fmaf(wb.x, hx, s1);
            s0 = fmaf(wa.y, hy, s0); s1 = fmaf(wb.y, hy, s1);
            s0 = fmaf(wa.z, hz, s0); s1 = fmaf(wb.z, hz, s1);
            s0 = fmaf(wa.w, hw, s0); s1 = fmaf(wb.w, hw, s1);
#pragma unroll
            for (int m = 32; m >= 1; m >>= 1) {
                s0 += __shfl_xor(s0, m, 64);
                s1 += __shfl_xor(s1, m, 64);
            }
        }
        if (lane == 0) { part[i & 1][w][0] = s0; part[i & 1][w][1] = s1; }
        __syncthreads();

        float p0 = __shfl(b3v, i, 64);
        float p1 = __shfl(b3v, NI + i, 64);
#pragma unroll
        for (int ww = 0; ww < WPB; ++ww) { p0 += part[i & 1][ww][0]; p1 += part[i & 1][ww][1]; }
        float a  = tanhf(p1);
        float xi = fmaf(__shfl(xin, i, 64), expf(a), p0);  // lane-uniform
        if (lane == 0) xsbuf[w][i] = xi;                   // own-wave copy, no barrier
        Jacc -= a;
    }

    if (w == 0 && lane < NI) out[row * NI + lane] = xsbuf[0][lane];
    if (tid == 0) out[B * NI + row] = Jacc;
}

extern "C" void kernel_launch(void* const* d_in, const int* in_sizes, int n_in,
                              void* d_out, int out_size, void* d_ws, size_t ws_size,
                              hipStream_t stream) {
    const float* inputs = (const float*)d_in[0];
    const float* W1     = (const float*)d_in[1];
    const float* b1     = (const float*)d_in[2];
    const float* W2     = (const float*)d_in[3];
    const float* b2     = (const float*)d_in[4];
    const float* W3     = (const float*)d_in[5];
    const float* b3     = (const float*)d_in[6];
    float* out = (float*)d_out;
    float* ws  = (float*)d_ws;

    prep_all<<<4484, 256, 0, stream>>>(W1, b1, W2, b2, W3, ws);
    made_scan<<<B, 256, 0, stream>>>(inputs, b3, ws, out);
}